// Round 1
// baseline (77917.798 us; speedup 1.0000x reference)
//
#include <hip/hip_runtime.h>

// LSTM: B=256, T=512, D=64, H=256, 2 layers, FC to O=4.
// Strategy: one workgroup (1024 threads) per batch element; thread t owns
// gate-row t (of 4H=1024) for both layers. All weights held in registers as
// fp16 pairs (416 half2 VGPRs/thread). h and x broadcast from LDS.
// Recurrent + input projections computed with v_dot2_f32_f16 (fp32 accum).
// No workspace, no cross-block communication.

#define BQ 256
#define TQ 512
#define DQ 64
#define HQ 256
#define NGQ 1024  // 4*H

typedef _Float16 h1t;
typedef __attribute__((ext_vector_type(2))) _Float16 h2t;

__device__ __forceinline__ h2t bc(float f) { return __builtin_bit_cast(h2t, f); }
__device__ __forceinline__ h2t pack2(float a, float b) {
    h2t r; r.x = (h1t)a; r.y = (h1t)b; return r;
}
__device__ __forceinline__ float sigmoidf_(float x) { return 1.f / (1.f + __expf(-x)); }
__device__ __forceinline__ float tanhf_(float x) {
    float e = __expf(2.f * x);
    return 1.f - 2.f / (e + 1.f);   // safe at +/-inf
}

// 8 MACs: one float4 = 4 packed half2 broadcast operands vs 4 weight half2
#define DOT8(vec, warr, base, acc)                                            \
    acc = __builtin_amdgcn_fdot2(bc((vec).x), (warr)[(base) + 0], acc, false); \
    acc = __builtin_amdgcn_fdot2(bc((vec).y), (warr)[(base) + 1], acc, false); \
    acc = __builtin_amdgcn_fdot2(bc((vec).z), (warr)[(base) + 2], acc, false); \
    acc = __builtin_amdgcn_fdot2(bc((vec).w), (warr)[(base) + 3], acc, false);

// load nf4 float4's of fp32 weights from row base, convert to half2 regs
#define LOADW(dst, srcptr, nf4)                                               \
    {                                                                         \
        const float4* p_ = reinterpret_cast<const float4*>(srcptr);           \
        _Pragma("unroll") for (int i_ = 0; i_ < (nf4); ++i_) {                \
            float4 v_ = p_[i_];                                               \
            (dst)[2 * i_]     = pack2(v_.x, v_.y);                            \
            (dst)[2 * i_ + 1] = pack2(v_.z, v_.w);                            \
        }                                                                     \
    }

__global__ __launch_bounds__(1024, 1) void lstm_fused(
    const float* __restrict__ x,
    const float* __restrict__ Wih0, const float* __restrict__ Whh0,
    const float* __restrict__ bih0, const float* __restrict__ bhh0,
    const float* __restrict__ Wih1, const float* __restrict__ Whh1,
    const float* __restrict__ bih1, const float* __restrict__ bhh1,
    const float* __restrict__ fcW, const float* __restrict__ fcb,
    float* __restrict__ out)
{
    __shared__ __align__(16) h2t   xs[TQ * DQ / 2];   // 64 KB: x[b] as fp16
    __shared__ __align__(16) float gates[NGQ];        // 4 KB
    __shared__ __align__(16) h2t   h0s[HQ / 2];       // layer0 h (fp16)
    __shared__ __align__(16) h2t   h1s[HQ / 2];       // layer1 h (fp16)
    __shared__ __align__(16) float h1f[HQ];           // layer1 h (fp32, for FC)
    __shared__ float partial[16];

    const int tid = threadIdx.x;
    const int b   = blockIdx.x;

    // ---- preload x[b] (T*D fp32, contiguous) into LDS as fp16, coalesced ----
    {
        const float4* xg = reinterpret_cast<const float4*>(x + (size_t)b * TQ * DQ);
#pragma unroll
        for (int i = 0; i < 8; ++i) {
            float4 v = xg[i * 1024 + tid];
            int e = (i * 1024 + tid) * 2;
            xs[e]     = pack2(v.x, v.y);
            xs[e + 1] = pack2(v.z, v.w);
        }
    }

    // ---- per-thread weight rows (row n = tid), fp32 -> fp16 registers ----
    h2t wih0[DQ / 2];   // 32 half2
    h2t whh0[HQ / 2];   // 128
    h2t wih1[HQ / 2];   // 128
    h2t whh1[HQ / 2];   // 128
    LOADW(wih0, Wih0 + (size_t)tid * DQ, 16);
    LOADW(whh0, Whh0 + (size_t)tid * HQ, 64);
    LOADW(wih1, Wih1 + (size_t)tid * HQ, 64);
    LOADW(whh1, Whh1 + (size_t)tid * HQ, 64);
    const float b0 = bih0[tid] + bhh0[tid];
    const float b1 = bih1[tid] + bhh1[tid];

    if (tid < HQ / 2) { h0s[tid] = pack2(0.f, 0.f); h1s[tid] = pack2(0.f, 0.f); }
    float c0 = 0.f, c1 = 0.f;
    __syncthreads();

    const float4* h0v = reinterpret_cast<const float4*>(h0s);
    const float4* h1v = reinterpret_cast<const float4*>(h1s);
    const float4* xv  = reinterpret_cast<const float4*>(xs);

    for (int t = 0; t < TQ; ++t) {
        // ---- layer 0: gates[n] = b0 + x_t . Wih0[n] + h0 . Whh0[n] ----
        float a = b0;
        {
            const float4* xt = xv + t * 8;   // 8 float4 = 64 halves
#pragma unroll
            for (int i = 0; i < 8; ++i) { float4 v = xt[i]; DOT8(v, wih0, 4 * i, a); }
#pragma unroll
            for (int i = 0; i < 32; ++i) { float4 v = h0v[i]; DOT8(v, whh0, 4 * i, a); }
        }
        gates[tid] = a;
        __syncthreads();

        if (tid < HQ) {
            float gi = gates[tid], gf = gates[HQ + tid];
            float gg = gates[2 * HQ + tid], go = gates[3 * HQ + tid];
            float fi = sigmoidf_(gi), ff = sigmoidf_(gf);
            float fg = tanhf_(gg), fo = sigmoidf_(go);
            c0 = ff * c0 + fi * fg;
            float h = fo * tanhf_(c0);
            reinterpret_cast<h1t*>(h0s)[tid] = (h1t)h;
        }
        __syncthreads();

        // ---- layer 1: gates[n] = b1 + h0_new . Wih1[n] + h1 . Whh1[n] ----
        float a1 = b1;
        {
#pragma unroll
            for (int i = 0; i < 32; ++i) { float4 v = h0v[i]; DOT8(v, wih1, 4 * i, a1); }
#pragma unroll
            for (int i = 0; i < 32; ++i) { float4 v = h1v[i]; DOT8(v, whh1, 4 * i, a1); }
        }
        gates[tid] = a1;
        __syncthreads();

        if (tid < HQ) {
            float gi = gates[tid], gf = gates[HQ + tid];
            float gg = gates[2 * HQ + tid], go = gates[3 * HQ + tid];
            float fi = sigmoidf_(gi), ff = sigmoidf_(gf);
            float fg = tanhf_(gg), fo = sigmoidf_(go);
            c1 = ff * c1 + fi * fg;
            float h = fo * tanhf_(c1);
            reinterpret_cast<h1t*>(h1s)[tid] = (h1t)h;
            h1f[tid] = h;   // fp32 copy; only last step's value is consumed
        }
        __syncthreads();
    }

    // ---- final FC: out[b][o] = fcb[o] + sum_j h1f[j] * fcW[o][j] ----
    {
        const int o = tid >> 8;          // 0..3, uniform within each wave
        const int j = tid & (HQ - 1);    // 0..255
        float p = h1f[j] * fcW[o * HQ + j];
#pragma unroll
        for (int off = 32; off; off >>= 1) p += __shfl_down(p, off);
        if ((tid & 63) == 0) partial[tid >> 6] = p;
        __syncthreads();
        if (tid < 4) {
            float s = fcb[tid];
#pragma unroll
            for (int w = 0; w < 4; ++w) s += partial[tid * 4 + w];
            out[b * 4 + tid] = s;
        }
    }
}

extern "C" void kernel_launch(void* const* d_in, const int* in_sizes, int n_in,
                              void* d_out, int out_size, void* d_ws, size_t ws_size,
                              hipStream_t stream)
{
    (void)in_sizes; (void)n_in; (void)d_ws; (void)ws_size; (void)out_size;
    const float* x    = (const float*)d_in[0];
    const float* Wih0 = (const float*)d_in[1];
    const float* Whh0 = (const float*)d_in[2];
    const float* bih0 = (const float*)d_in[3];
    const float* bhh0 = (const float*)d_in[4];
    const float* Wih1 = (const float*)d_in[5];
    const float* Whh1 = (const float*)d_in[6];
    const float* bih1 = (const float*)d_in[7];
    const float* bhh1 = (const float*)d_in[8];
    const float* fcW  = (const float*)d_in[9];
    const float* fcb  = (const float*)d_in[10];
    float* out = (float*)d_out;

    lstm_fused<<<dim3(BQ), dim3(1024), 0, stream>>>(
        x, Wih0, Whh0, bih0, bhh0, Wih1, Whh1, bih1, bhh1, fcW, fcb, out);
}

// Round 3
// 10225.696 us; speedup vs baseline: 7.6198x; 7.6198x over previous
//
#include <hip/hip_runtime.h>

// 2-layer LSTM (B=256, T=512, D=64, H=256) + FC(256->4).
// Design: weight-distributed persistent kernel.
//   32 groups x 8 blocks; group handles 8 batch elements.
//   Blocks 0-3 of a group: layer 0, h-index quadrant q (64 h-idx = 256 gate rows).
//   Blocks 4-7: layer 1, quadrant q. Systolic skew: at super-step s, L0 computes
//   h0(s), L1 computes h1(s-1). One group barrier per super-step (513 total),
//   device-scope atomics + agent fences for cross-XCD h visibility.
// Per-thread weights: <=128 packed-fp16 u32 in registers (512 thr => 256 VGPR cap).
// h state: fp16 in d_ws global double buffers (256KB+256KB) + group counters.

#define TT 512
#define HH 256
#define DD 64

typedef __attribute__((ext_vector_type(2))) _Float16 h2t;

__device__ __forceinline__ h2t f2h2(float f) { return __builtin_bit_cast(h2t, f); }
__device__ __forceinline__ h2t u2h2(unsigned u) { return __builtin_bit_cast(h2t, u); }
__device__ __forceinline__ unsigned pkh(float x, float y) {
    h2t h; h.x = (_Float16)x; h.y = (_Float16)y;
    return __builtin_bit_cast(unsigned, h);
}
__device__ __forceinline__ float sigf(float x) { return 1.f / (1.f + __expf(-x)); }
__device__ __forceinline__ float tanhf_(float x) {
    float e = __expf(2.f * x);
    return 1.f - 2.f / (e + 1.f);   // safe at +/-inf
}

// 8 MACs: one float4 (4 packed half2) vs wh[b..b+3]; indices constant post-unroll
#define Q4(vv, b)                                                                \
    a = __builtin_amdgcn_fdot2(f2h2((vv).x), u2h2(wh[(b) + 0]), a, false);       \
    a = __builtin_amdgcn_fdot2(f2h2((vv).y), u2h2(wh[(b) + 1]), a, false);       \
    a = __builtin_amdgcn_fdot2(f2h2((vv).z), u2h2(wh[(b) + 2]), a, false);       \
    a = __builtin_amdgcn_fdot2(f2h2((vv).w), u2h2(wh[(b) + 3]), a, false);

__global__ __launch_bounds__(512, 2) void lstm_persist(
    const float* __restrict__ x,
    const float* __restrict__ Wih0, const float* __restrict__ Whh0,
    const float* __restrict__ bih0, const float* __restrict__ bhh0,
    const float* __restrict__ Wih1, const float* __restrict__ Whh1,
    const float* __restrict__ bih1, const float* __restrict__ bhh1,
    const float* __restrict__ fcW, const float* __restrict__ fcb,
    float* __restrict__ out,
    unsigned short* h0buf, unsigned short* h1buf, unsigned* counters)
{
    __shared__ __align__(16) unsigned short sh0[8][HH];   // 4 KB  h0(s-1), 8 batch
    __shared__ __align__(16) unsigned short sh1[8][HH];   // 4 KB  h1(s-2)
    __shared__ __align__(16) unsigned short sx[8][DD];    // 1 KB  x(s) fp16
    __shared__ __align__(16) float part[2][8][256];       // 16 KB k-split partials

    const int tid   = threadIdx.x;
    const int g     = blockIdx.x >> 3;
    const int role  = blockIdx.x & 7;
    const bool isL1 = role >= 4;
    const int q     = isL1 ? role - 4 : role;     // h-index quadrant
    const int batch0 = g * 8;
    unsigned* cnt = counters + (size_t)g * 16;    // 64B-padded per-group counter

    const int r  = tid & 255;     // local gate row
    const int kh = tid >> 8;      // k-split half
    const int gq = r >> 6;        // gate 0..3 (i,f,g,o)
    const int ii = r & 63;        // h-index within quadrant
    const int R  = 256 * gq + 64 * q + ii;   // global gate row

    // ---- load this thread's weight slice as packed fp16 (registers) ----
    unsigned wh[128];
    if (isL1) {
        const float* Wsel = kh ? Whh1 : Wih1;     // kh0: h0 operand, kh1: h1 operand
        const float2* p = reinterpret_cast<const float2*>(Wsel + (size_t)R * HH);
#pragma unroll
        for (int i = 0; i < 128; ++i) { float2 v = p[i]; wh[i] = pkh(v.x, v.y); }
    } else if (kh == 0) {
        // x-part (64 halves) + h0[0:64]
        const float2* p = reinterpret_cast<const float2*>(Wih0 + (size_t)R * DD);
#pragma unroll
        for (int i = 0; i < 32; ++i) { float2 v = p[i]; wh[i] = pkh(v.x, v.y); }
        const float2* p2 = reinterpret_cast<const float2*>(Whh0 + (size_t)R * HH);
#pragma unroll
        for (int i = 0; i < 32; ++i) { float2 v = p2[i]; wh[32 + i] = pkh(v.x, v.y); }
    } else {
        // h0[64:256]
        const float2* p = reinterpret_cast<const float2*>(Whh0 + (size_t)R * HH + 64);
#pragma unroll
        for (int i = 0; i < 96; ++i) { float2 v = p[i]; wh[i] = pkh(v.x, v.y); }
    }

    // ---- activation-duty setup: thread (i2, j2); biases + register c-state ----
    const int i2 = tid & 63, j2 = tid >> 6;   // j2 in 0..7
    const float* bA = isL1 ? bih1 : bih0;
    const float* bB = isL1 ? bhh1 : bhh0;
    const float bz0 = bA[0 * 256 + 64 * q + i2] + bB[0 * 256 + 64 * q + i2];
    const float bz1 = bA[1 * 256 + 64 * q + i2] + bB[1 * 256 + 64 * q + i2];
    const float bz2 = bA[2 * 256 + 64 * q + i2] + bB[2 * 256 + 64 * q + i2];
    const float bz3 = bA[3 * 256 + 64 * q + i2] + bB[3 * 256 + 64 * q + i2];
    float cst = 0.f;

    for (int s = 0; s <= TT; ++s) {
        const bool active = isL1 ? (s >= 1) : (s < TT);

        // ---- stage h (and x for L0) into LDS, coalesced ----
        if (active) {
            if (!isL1) {
                if (tid < 256) {               // h0(s-1): parity (s-1)&1 == (s+1)&1
                    int j = tid >> 5, c = tid & 31;
                    const float4* src = reinterpret_cast<const float4*>(
                        h0buf + ((size_t)((s + 1) & 1) * 256 + batch0 + j) * HH);
                    reinterpret_cast<float4*>(&sh0[j][0])[c] = src[c];
                } else if (tid < 384) {        // x(s) -> fp16
                    int t2 = tid - 256; int j = t2 >> 4, c = t2 & 15;
                    const float4* src = reinterpret_cast<const float4*>(
                        x + ((size_t)(batch0 + j) * TT + s) * DD);
                    float4 v = src[c];
                    unsigned* dst = reinterpret_cast<unsigned*>(&sx[j][0]);
                    dst[2 * c] = pkh(v.x, v.y); dst[2 * c + 1] = pkh(v.z, v.w);
                }
            } else {
                if (tid < 256) {               // h0(s-1)
                    int j = tid >> 5, c = tid & 31;
                    const float4* src = reinterpret_cast<const float4*>(
                        h0buf + ((size_t)((s + 1) & 1) * 256 + batch0 + j) * HH);
                    reinterpret_cast<float4*>(&sh0[j][0])[c] = src[c];
                } else {                       // h1(s-2): parity (s-2)&1 == s&1
                    int t2 = tid - 256; int j = t2 >> 5, c = t2 & 31;
                    const float4* src = reinterpret_cast<const float4*>(
                        h1buf + ((size_t)(s & 1) * 256 + batch0 + j) * HH);
                    reinterpret_cast<float4*>(&sh1[j][0])[c] = src[c];
                }
            }
        }
        __syncthreads();

        // ---- compute partial gate dots; write part[kh][j][r] ----
        if (active) {
            if (isL1) {
                const float4* hb = reinterpret_cast<const float4*>(kh ? &sh1[0][0] : &sh0[0][0]);
#pragma unroll
                for (int j = 0; j < 8; ++j) {
                    const float4* hj = hb + j * 32;
                    float a = 0.f;
#pragma unroll
                    for (int c = 0; c < 32; ++c) { float4 v = hj[c]; Q4(v, 4 * c) }
                    part[kh][j][r] = a;
                }
            } else if (kh == 0) {
#pragma unroll
                for (int j = 0; j < 8; ++j) {
                    const float4* xj = reinterpret_cast<const float4*>(&sx[j][0]);
                    const float4* hj = reinterpret_cast<const float4*>(&sh0[j][0]);
                    float a = 0.f;
#pragma unroll
                    for (int c = 0; c < 8; ++c) { float4 v = xj[c]; Q4(v, 4 * c) }
#pragma unroll
                    for (int c = 0; c < 8; ++c) { float4 v = hj[c]; Q4(v, 32 + 4 * c) }
                    part[0][j][r] = a;
                }
            } else {
#pragma unroll
                for (int j = 0; j < 8; ++j) {
                    const float4* hj = reinterpret_cast<const float4*>(&sh0[j][0]);
                    float a = 0.f;
#pragma unroll
                    for (int c = 8; c < 32; ++c) { float4 v = hj[c]; Q4(v, 4 * (c - 8)) }
                    part[1][j][r] = a;
                }
            }
        }
        __syncthreads();

        // ---- activation: thread (i2, j2) owns one (h-idx, batch); c in register ----
        if (active) {
            float s0 = part[0][j2][(0 << 6) | i2] + part[1][j2][(0 << 6) | i2] + bz0;
            float s1 = part[0][j2][(1 << 6) | i2] + part[1][j2][(1 << 6) | i2] + bz1;
            float s2 = part[0][j2][(2 << 6) | i2] + part[1][j2][(2 << 6) | i2] + bz2;
            float s3 = part[0][j2][(3 << 6) | i2] + part[1][j2][(3 << 6) | i2] + bz3;
            float fi = sigf(s0), ff = sigf(s1), fg = tanhf_(s2), fo = sigf(s3);
            cst = ff * cst + fi * fg;
            float h = fo * tanhf_(cst);
            unsigned short hb16 = __builtin_bit_cast(unsigned short, (_Float16)h);
            if (!isL1)
                h0buf[((size_t)(s & 1) * 256 + batch0 + j2) * HH + 64 * q + i2] = hb16;
            else
                h1buf[((size_t)((s - 1) & 1) * 256 + batch0 + j2) * HH + 64 * q + i2] = hb16;
        }
        __syncthreads();   // drains each wave's stores (vmcnt0) before barrier

        // ---- group barrier: release writes, arrive, spin-acquire ----
        if (tid == 0) {
            __threadfence();   // agent-scope release (L2 writeback for cross-XCD)
            __hip_atomic_fetch_add(cnt, 1u, __ATOMIC_ACQ_REL, __HIP_MEMORY_SCOPE_AGENT);
            const unsigned target = 8u * (unsigned)(s + 1);
            while (__hip_atomic_load(cnt, __ATOMIC_ACQUIRE, __HIP_MEMORY_SCOPE_AGENT) < target)
                __builtin_amdgcn_s_sleep(2);
            __threadfence();   // acquire-invalidate for stale L1/L2 lines
        }
        __syncthreads();
    }

    // ---- final FC on h1(T-1) (parity 1), done by the q==0 L1 block per group ----
    if (isL1 && q == 0 && tid < 32) {
        int j = tid >> 2, o = tid & 3;
        const unsigned short* hrow = h1buf + ((size_t)1 * 256 + batch0 + j) * HH;
        float sum = fcb[o];
        for (int k = 0; k < HH; ++k) {
            _Float16 hv = __builtin_bit_cast(_Float16, hrow[k]);
            sum += (float)hv * fcW[o * HH + k];
        }
        out[(batch0 + j) * 4 + o] = sum;
    }
}

extern "C" void kernel_launch(void* const* d_in, const int* in_sizes, int n_in,
                              void* d_out, int out_size, void* d_ws, size_t ws_size,
                              hipStream_t stream)
{
    (void)in_sizes; (void)n_in; (void)out_size; (void)ws_size;
    const float* x    = (const float*)d_in[0];
    const float* Wih0 = (const float*)d_in[1];
    const float* Whh0 = (const float*)d_in[2];
    const float* bih0 = (const float*)d_in[3];
    const float* bhh0 = (const float*)d_in[4];
    const float* Wih1 = (const float*)d_in[5];
    const float* Whh1 = (const float*)d_in[6];
    const float* bih1 = (const float*)d_in[7];
    const float* bhh1 = (const float*)d_in[8];
    const float* fcW  = (const float*)d_in[9];
    const float* fcb  = (const float*)d_in[10];
    float* out = (float*)d_out;

    // ws layout: h0buf 2x256x256 fp16 (256KB) | h1buf (256KB) | counters (2KB)
    unsigned short* h0buf = (unsigned short*)d_ws;
    unsigned short* h1buf = (unsigned short*)((char*)d_ws + 262144);
    unsigned*       cnts  = (unsigned*)((char*)d_ws + 524288);

    hipMemsetAsync(d_ws, 0, 524288 + 2048, stream);   // zero h bufs + counters

    lstm_persist<<<dim3(256), dim3(512), 0, stream>>>(
        x, Wih0, Whh0, bih0, bhh0, Wih1, Whh1, bih1, bhh1, fcW, fcb, out,
        h0buf, h1buf, cnts);
}

// Round 5
// 3822.932 us; speedup vs baseline: 20.3817x; 2.6748x over previous
//
#include <hip/hip_runtime.h>

// 2-layer LSTM (B=256, T=512, D=64, H=256) + FC(256->4).
// 32 groups x 8 blocks; group = 8 batch elements. Roles: blocks 0-3 layer 0
// (h-quadrant q), blocks 4-7 layer 1. Systolic skew: at super-step s, L0
// computes h0(s), L1 computes h1(s-1). Sync = per-block epoch flags with
// relaxed agent-scope atomics (no threadfence/wbl2, no RMW barrier).
// Weights: 16 named u32x8 ext-vectors per thread (<=128 VGPRs packed fp16).
// Round-4 bug fixed here: u64-unit addressing of h buffers (parity stride
// 16384 u64 = 131072 B, batch stride 64 u64 = 512 B; previously /8 instead
// of /4 when converting u16 counts -> u64 indices).

#define TT 512
#define HH 256
#define DD 64

typedef __attribute__((ext_vector_type(2))) _Float16 h2t;
typedef __attribute__((ext_vector_type(8))) unsigned u8v;
typedef unsigned long long u64;

__device__ __forceinline__ h2t f2h2(float f) { return __builtin_bit_cast(h2t, f); }
__device__ __forceinline__ h2t u2h2(unsigned u) { return __builtin_bit_cast(h2t, u); }
__device__ __forceinline__ unsigned pkh(float x, float y) {
    h2t h; h.x = (_Float16)x; h.y = (_Float16)y;
    return __builtin_bit_cast(unsigned, h);
}
__device__ __forceinline__ float sigf(float x) { return 1.f / (1.f + __expf(-x)); }
__device__ __forceinline__ float tanhf_(float x) {
    float e = __expf(2.f * x);
    return 1.f - 2.f / (e + 1.f);   // safe at +/-inf
}

// 16 consecutive fp32 -> one u8v of 8 packed half2
__device__ __forceinline__ u8v ldw16(const float* p) {
    const float4* q = reinterpret_cast<const float4*>(p);
    float4 A = q[0], B = q[1], C = q[2], D = q[3];
    u8v r;
    r.s0 = pkh(A.x, A.y); r.s1 = pkh(A.z, A.w);
    r.s2 = pkh(B.x, B.y); r.s3 = pkh(B.z, B.w);
    r.s4 = pkh(C.x, C.y); r.s5 = pkh(C.z, C.w);
    r.s6 = pkh(D.x, D.y); r.s7 = pkh(D.z, D.w);
    return r;
}

// 16 MACs: u8v weights vs 16 broadcast halves (two float4 = 8 packed half2)
__device__ __forceinline__ float dotu8(u8v w, float4 a, float4 b, float acc) {
    acc = __builtin_amdgcn_fdot2(f2h2(a.x), u2h2(w.s0), acc, false);
    acc = __builtin_amdgcn_fdot2(f2h2(a.y), u2h2(w.s1), acc, false);
    acc = __builtin_amdgcn_fdot2(f2h2(a.z), u2h2(w.s2), acc, false);
    acc = __builtin_amdgcn_fdot2(f2h2(a.w), u2h2(w.s3), acc, false);
    acc = __builtin_amdgcn_fdot2(f2h2(b.x), u2h2(w.s4), acc, false);
    acc = __builtin_amdgcn_fdot2(f2h2(b.y), u2h2(w.s5), acc, false);
    acc = __builtin_amdgcn_fdot2(f2h2(b.z), u2h2(w.s6), acc, false);
    acc = __builtin_amdgcn_fdot2(f2h2(b.w), u2h2(w.s7), acc, false);
    return acc;
}

__device__ __forceinline__ unsigned ldflag(const unsigned* p) {
    return __hip_atomic_load(p, __ATOMIC_RELAXED, __HIP_MEMORY_SCOPE_AGENT);
}
__device__ __forceinline__ u64 ld64(const u64* p) {
    return __hip_atomic_load(p, __ATOMIC_RELAXED, __HIP_MEMORY_SCOPE_AGENT);
}

__global__ __launch_bounds__(512, 2) void lstm_persist(
    const float* __restrict__ x,
    const float* __restrict__ Wih0, const float* __restrict__ Whh0,
    const float* __restrict__ bih0, const float* __restrict__ bhh0,
    const float* __restrict__ Wih1, const float* __restrict__ Whh1,
    const float* __restrict__ bih1, const float* __restrict__ bhh1,
    const float* __restrict__ fcW, const float* __restrict__ fcb,
    float* __restrict__ out,
    unsigned short* h0buf, unsigned short* h1buf, unsigned* counters)
{
    __shared__ __align__(16) unsigned short sh0[8][HH];   // 4 KB  h0(s-1)
    __shared__ __align__(16) unsigned short sh1[8][HH];   // 4 KB  h1(s-2)
    __shared__ __align__(16) unsigned short sx[8][DD];    // 1 KB  x(s) fp16
    __shared__ __align__(16) float part[2][8][256];       // 16 KB partials

    const int tid   = threadIdx.x;
    const int g     = blockIdx.x >> 3;
    const int role  = blockIdx.x & 7;
    const bool isL1 = role >= 4;
    const int q     = isL1 ? role - 4 : role;
    const int batch0 = g * 8;
    unsigned* flags = counters + (size_t)g * 16;   // 8 u32 flags, 64B padded

    const int r  = tid & 255;     // local gate row
    const int kh = tid >> 8;      // k-split half
    const int gq = r >> 6;        // gate 0..3 (i,f,g,o)
    const int ii = r & 63;        // h-index within quadrant
    const int R  = 256 * gq + 64 * q + ii;   // global gate row

    // ---- weights: 16 named u8v (SSA, constant extracts only) ----
    u8v w0 = {}, w1 = {}, w2 = {}, w3 = {}, w4 = {}, w5 = {}, w6 = {}, w7 = {};
    u8v w8 = {}, w9 = {}, w10 = {}, w11 = {}, w12 = {}, w13 = {}, w14 = {}, w15 = {};
    if (isL1) {
        const float* row = (kh ? Whh1 : Wih1) + (size_t)R * HH;
        w0  = ldw16(row +   0); w1  = ldw16(row +  16);
        w2  = ldw16(row +  32); w3  = ldw16(row +  48);
        w4  = ldw16(row +  64); w5  = ldw16(row +  80);
        w6  = ldw16(row +  96); w7  = ldw16(row + 112);
        w8  = ldw16(row + 128); w9  = ldw16(row + 144);
        w10 = ldw16(row + 160); w11 = ldw16(row + 176);
        w12 = ldw16(row + 192); w13 = ldw16(row + 208);
        w14 = ldw16(row + 224); w15 = ldw16(row + 240);
    } else if (kh == 0) {
        const float* ra = Wih0 + (size_t)R * DD;       // x part, 64 halves
        w0 = ldw16(ra); w1 = ldw16(ra + 16); w2 = ldw16(ra + 32); w3 = ldw16(ra + 48);
        const float* rb = Whh0 + (size_t)R * HH;       // h0[0:64]
        w4 = ldw16(rb); w5 = ldw16(rb + 16); w6 = ldw16(rb + 32); w7 = ldw16(rb + 48);
    } else {
        const float* rb = Whh0 + (size_t)R * HH + 64;  // h0[64:256]
        w0  = ldw16(rb +   0); w1  = ldw16(rb +  16);
        w2  = ldw16(rb +  32); w3  = ldw16(rb +  48);
        w4  = ldw16(rb +  64); w5  = ldw16(rb +  80);
        w6  = ldw16(rb +  96); w7  = ldw16(rb + 112);
        w8  = ldw16(rb + 128); w9  = ldw16(rb + 144);
        w10 = ldw16(rb + 160); w11 = ldw16(rb + 176);
    }

    // ---- activation duty: thread (i2 = lane, j2 = wave) ----
    const int i2 = tid & 63, j2 = tid >> 6;
    const float* bA = isL1 ? bih1 : bih0;
    const float* bB = isL1 ? bhh1 : bhh0;
    const float bz0 = bA[0 * 256 + 64 * q + i2] + bB[0 * 256 + 64 * q + i2];
    const float bz1 = bA[1 * 256 + 64 * q + i2] + bB[1 * 256 + 64 * q + i2];
    const float bz2 = bA[2 * 256 + 64 * q + i2] + bB[2 * 256 + 64 * q + i2];
    const float bz3 = bA[3 * 256 + 64 * q + i2] + bB[3 * 256 + 64 * q + i2];
    float cst = 0.f;

    // u64-unit strides: parity = 16384 u64 (131072 B), batch = 64 u64 (512 B)
    const u64* h0u = reinterpret_cast<const u64*>(h0buf);
    const u64* h1u = reinterpret_cast<const u64*>(h1buf);

    for (int s = 0; s <= TT; ++s) {
        const bool active = isL1 ? (s >= 1) : (s < TT);

        // prefetch x(s) into regs (no flag dependency)
        float4 xp;
        const bool doX = (!isL1) && (s < TT) && (tid >= 256) && (tid < 384);
        if (doX) {
            int t2 = tid - 256, j = t2 >> 4, c = t2 & 15;
            xp = reinterpret_cast<const float4*>(
                     x + ((size_t)(batch0 + j) * TT + s) * DD)[c];
        }

        // ---- epoch wait: all 8 blocks finished step s-1 ----
        if (s > 0 && tid < 8) {
            while (ldflag(&flags[tid]) < (unsigned)s) __builtin_amdgcn_s_sleep(1);
        }
        __syncthreads();

        // ---- stage h (+x) into LDS ----
        if (active) {
            // sh0 <- h0(s-1), parity (s+1)&1: 512 u64, one per thread
            reinterpret_cast<u64*>(sh0)[tid] =
                ld64(h0u + (size_t)((s + 1) & 1) * 16384 + batch0 * 64 + tid);
            if (isL1) {  // sh1 <- h1(s-2), parity s&1
                reinterpret_cast<u64*>(sh1)[tid] =
                    ld64(h1u + (size_t)(s & 1) * 16384 + batch0 * 64 + tid);
            } else if (doX) {
                int t2 = tid - 256, j = t2 >> 4, c = t2 & 15;
                unsigned* dst = reinterpret_cast<unsigned*>(&sx[j][0]);
                dst[2 * c] = pkh(xp.x, xp.y); dst[2 * c + 1] = pkh(xp.z, xp.w);
            }
        }
        __syncthreads();

        // ---- partial gate dots -> part[kh][j][r] ----
        if (active) {
            if (isL1) {
                const float4* hb = reinterpret_cast<const float4*>(kh ? &sh1[0][0] : &sh0[0][0]);
#pragma unroll 2
                for (int j = 0; j < 8; ++j) {
                    const float4* hj = hb + j * 32;
                    float a0 = 0.f, a1 = 0.f;
#define E2(i0, i1) a0 = dotu8(w##i0, hj[2*i0], hj[2*i0+1], a0); \
                   a1 = dotu8(w##i1, hj[2*i1], hj[2*i1+1], a1);
                    E2(0, 1) E2(2, 3) E2(4, 5) E2(6, 7)
                    E2(8, 9) E2(10, 11) E2(12, 13) E2(14, 15)
#undef E2
                    part[kh][j][r] = a0 + a1;
                }
            } else if (kh == 0) {
#pragma unroll 2
                for (int j = 0; j < 8; ++j) {
                    const float4* xj = reinterpret_cast<const float4*>(&sx[j][0]);
                    const float4* hj = reinterpret_cast<const float4*>(&sh0[j][0]);
                    float a0 = 0.f, a1 = 0.f;
                    a0 = dotu8(w0, xj[0], xj[1], a0); a1 = dotu8(w1, xj[2], xj[3], a1);
                    a0 = dotu8(w2, xj[4], xj[5], a0); a1 = dotu8(w3, xj[6], xj[7], a1);
                    a0 = dotu8(w4, hj[0], hj[1], a0); a1 = dotu8(w5, hj[2], hj[3], a1);
                    a0 = dotu8(w6, hj[4], hj[5], a0); a1 = dotu8(w7, hj[6], hj[7], a1);
                    part[0][j][r] = a0 + a1;
                }
            } else {
#pragma unroll 2
                for (int j = 0; j < 8; ++j) {
                    const float4* hj = reinterpret_cast<const float4*>(&sh0[j][0]);
                    float a0 = 0.f, a1 = 0.f;
#define F2(i0, i1) a0 = dotu8(w##i0, hj[8+2*i0], hj[9+2*i0], a0); \
                   a1 = dotu8(w##i1, hj[8+2*i1], hj[9+2*i1], a1);
                    F2(0, 1) F2(2, 3) F2(4, 5) F2(6, 7) F2(8, 9) F2(10, 11)
#undef F2
                    part[1][j][r] = a0 + a1;
                }
            }
        }
        __syncthreads();

        // ---- activation; packed u64 relaxed-agent h store ----
        if (active) {
            float s0 = part[0][j2][(0 << 6) | i2] + part[1][j2][(0 << 6) | i2] + bz0;
            float s1 = part[0][j2][(1 << 6) | i2] + part[1][j2][(1 << 6) | i2] + bz1;
            float s2 = part[0][j2][(2 << 6) | i2] + part[1][j2][(2 << 6) | i2] + bz2;
            float s3 = part[0][j2][(3 << 6) | i2] + part[1][j2][(3 << 6) | i2] + bz3;
            float fi = sigf(s0), ff = sigf(s1), fg = tanhf_(s2), fo = sigf(s3);
            cst = ff * cst + fi * fg;
            float h = fo * tanhf_(cst);

            float hn = __shfl_down(h, 1);
            unsigned lo = pkh(h, hn);
            unsigned hi = __shfl_down(lo, 2);
            if ((i2 & 3) == 0) {
                u64 v = (u64)lo | ((u64)hi << 32);
                unsigned short* base = isL1
                    ? h1buf + (size_t)((s - 1) & 1) * 65536
                    : h0buf + (size_t)(s & 1) * 65536;
                u64* dst = reinterpret_cast<u64*>(base + (size_t)(batch0 + j2) * HH + 64 * q + i2);
                __hip_atomic_store(dst, v, __ATOMIC_RELAXED, __HIP_MEMORY_SCOPE_AGENT);
            }
        }
        asm volatile("s_waitcnt vmcnt(0)" ::: "memory");
        __syncthreads();   // all threads' h stores are at the coherence point

        if (tid == 0)
            __hip_atomic_store(&flags[role], (unsigned)(s + 1),
                               __ATOMIC_RELAXED, __HIP_MEMORY_SCOPE_AGENT);
    }

    // ---- final FC on h1(T-1) (parity 1), by the q==0 L1 block per group ----
    if (isL1 && q == 0) {
        if (tid < 4) {
            while (ldflag(&flags[4 + tid]) < (unsigned)(TT + 1)) __builtin_amdgcn_s_sleep(1);
        }
        __syncthreads();
        reinterpret_cast<u64*>(sh1)[tid] = ld64(h1u + 16384 + batch0 * 64 + tid);
        __syncthreads();

        const int j = tid >> 6, lane = tid & 63;
        const int o = lane >> 4, kk = lane & 15;
        float ssum = 0.f;
#pragma unroll
        for (int m = 0; m < 16; ++m) {
            int k = kk * 16 + m;
            ssum += (float)__builtin_bit_cast(_Float16, sh1[j][k]) * fcW[o * HH + k];
        }
#pragma unroll
        for (int off = 8; off; off >>= 1) ssum += __shfl_down(ssum, off);
        if (kk == 0) out[(batch0 + j) * 4 + o] = ssum + fcb[o];
    }
}

extern "C" void kernel_launch(void* const* d_in, const int* in_sizes, int n_in,
                              void* d_out, int out_size, void* d_ws, size_t ws_size,
                              hipStream_t stream)
{
    (void)in_sizes; (void)n_in; (void)out_size; (void)ws_size;
    const float* x    = (const float*)d_in[0];
    const float* Wih0 = (const float*)d_in[1];
    const float* Whh0 = (const float*)d_in[2];
    const float* bih0 = (const float*)d_in[3];
    const float* bhh0 = (const float*)d_in[4];
    const float* Wih1 = (const float*)d_in[5];
    const float* Whh1 = (const float*)d_in[6];
    const float* bih1 = (const float*)d_in[7];
    const float* bhh1 = (const float*)d_in[8];
    const float* fcW  = (const float*)d_in[9];
    const float* fcb  = (const float*)d_in[10];
    float* out = (float*)d_out;

    // ws: h0buf 2x256x256 fp16 (256KB) | h1buf (256KB) | flags (2KB)
    unsigned short* h0buf = (unsigned short*)d_ws;
    unsigned short* h1buf = (unsigned short*)((char*)d_ws + 262144);
    unsigned*       cnts  = (unsigned*)((char*)d_ws + 524288);

    hipMemsetAsync(d_ws, 0, 524288 + 2048, stream);

    lstm_persist<<<dim3(256), dim3(512), 0, stream>>>(
        x, Wih0, Whh0, bih0, bhh0, Wih1, Whh1, bih1, bhh1, fcW, fcb, out,
        h0buf, h1buf, cnts);
}